// Round 1
// baseline (969.213 us; speedup 1.0000x reference)
//
#include <hip/hip_runtime.h>

#define N_NODES 50000
#define N_EDGES 1600000
#define DIM     128
#define NLAYERS 3
#define NGRAPHS 64

// ---------------------------------------------------------------- utilities
__global__ __launch_bounds__(256) void zero_kernel(int* __restrict__ p, int n) {
    int i = blockIdx.x * 256 + threadIdx.x;
    if (i < n) p[i] = 0;
}

// ---------------------------------------------------------------- CSR build
__global__ __launch_bounds__(256) void hist_kernel(const int* __restrict__ dst,
                                                   int* __restrict__ cnt) {
    int e = blockIdx.x * 256 + threadIdx.x;
    if (e < N_EDGES) atomicAdd(&cnt[dst[e]], 1);
}

__global__ __launch_bounds__(256) void scan1_kernel(const int* __restrict__ cnt,
                                                    int* __restrict__ incl,
                                                    int* __restrict__ bsums) {
    __shared__ int sh[256];
    int i = blockIdx.x * 256 + threadIdx.x;
    int v = (i < N_NODES) ? cnt[i] : 0;
    sh[threadIdx.x] = v;
    __syncthreads();
    for (int o = 1; o < 256; o <<= 1) {
        int t = (threadIdx.x >= o) ? sh[threadIdx.x - o] : 0;
        __syncthreads();
        sh[threadIdx.x] += t;
        __syncthreads();
    }
    if (i < N_NODES) incl[i] = sh[threadIdx.x];
    if (threadIdx.x == 255) bsums[blockIdx.x] = sh[255];
}

__global__ __launch_bounds__(256) void scan2_kernel(int* __restrict__ bsums, int nb) {
    __shared__ int sh[256];
    int v = (threadIdx.x < nb) ? bsums[threadIdx.x] : 0;
    sh[threadIdx.x] = v;
    __syncthreads();
    for (int o = 1; o < 256; o <<= 1) {
        int t = (threadIdx.x >= o) ? sh[threadIdx.x - o] : 0;
        __syncthreads();
        sh[threadIdx.x] += t;
        __syncthreads();
    }
    if (threadIdx.x < nb) bsums[threadIdx.x] = sh[threadIdx.x] - v;  // exclusive
}

__global__ __launch_bounds__(256) void scan3_kernel(const int* __restrict__ incl,
                                                    const int* __restrict__ cnt,
                                                    const int* __restrict__ bsums,
                                                    int* __restrict__ row_start,
                                                    int* __restrict__ cursor) {
    int i = blockIdx.x * 256 + threadIdx.x;
    if (i < N_NODES) {
        int rs = incl[i] - cnt[i] + bsums[blockIdx.x];
        row_start[i] = rs;
        cursor[i]    = rs;
    }
}

// pack src (<65536) | type<<16 into one int; ordering within a row is
// nondeterministic but the fp32 sum is tolerance-equivalent.
__global__ __launch_bounds__(256) void fill_kernel(const int* __restrict__ src,
                                                   const int* __restrict__ dst,
                                                   const int* __restrict__ et,
                                                   int* __restrict__ cursor,
                                                   int* __restrict__ col) {
    int e = blockIdx.x * 256 + threadIdx.x;
    if (e < N_EDGES) {
        int d = dst[e];
        int p = atomicAdd(&cursor[d], 1);
        col[p] = src[e] | (et[e] << 16);
    }
}

// ---------------------------------------------------------------- fused 3-GEMM
// Computes O0 = X@W0+b0, O1 = X@W1+b1, O2 = X@W2+b2 for one layer.
// Tile: 64 rows x 128 cols, 256 threads, micro-tile 8 rows x 4 cols.
// Xs staged once per block (row-major, +4 pad -> 2-way-broadcast LDS reads, free);
// W streamed in 32-row k-chunks (16 KB). LDS total ~49 KB -> 3 blocks/CU.
__global__ __launch_bounds__(256) void gemm3_kernel(
        const float* __restrict__ X,
        const float* __restrict__ W0, const float* __restrict__ b0,
        const float* __restrict__ W1, const float* __restrict__ b1,
        const float* __restrict__ W2, const float* __restrict__ b2,
        float* __restrict__ O0, float* __restrict__ O1, float* __restrict__ O2) {
    __shared__ float Xs[64][132];
    __shared__ float WL[32][128];

    const int tid = threadIdx.x;
    const int tx  = tid & 31;   // cols tx*4 .. tx*4+3
    const int ty  = tid >> 5;   // rows ty*8 .. ty*8+7
    const int r0  = blockIdx.x * 64;

    // stage X tile (coalesced float4, conflict-free LDS writes)
    {
        const int rr = tid >> 5;
        const int k4 = (tid & 31) * 4;
#pragma unroll
        for (int p = 0; p < 8; ++p) {
            int row  = p * 8 + rr;
            float4 v = make_float4(0.f, 0.f, 0.f, 0.f);
            if (r0 + row < N_NODES)
                v = *(const float4*)(X + (size_t)(r0 + row) * DIM + k4);
            *(float4*)(&Xs[row][k4]) = v;
        }
    }

    const float* Wz[3] = {W0, W1, W2};
    const float* bz[3] = {b0, b1, b2};
    float* Oz[3]       = {O0, O1, O2};

    for (int w = 0; w < 3; ++w) {
        const float* Wg = Wz[w];
        float4 bias     = *(const float4*)(bz[w] + tx * 4);
        float acc[8][4];
#pragma unroll
        for (int i = 0; i < 8; ++i) {
            acc[i][0] = bias.x; acc[i][1] = bias.y;
            acc[i][2] = bias.z; acc[i][3] = bias.w;
        }
        for (int kc = 0; kc < 4; ++kc) {
            __syncthreads();
#pragma unroll
            for (int p = 0; p < 4; ++p) {
                int idx = p * 256 + tid;
                int kk  = idx >> 5;
                int c4  = (idx & 31) * 4;
                *(float4*)(&WL[kk][c4]) =
                    *(const float4*)(Wg + (size_t)(kc * 32 + kk) * DIM + c4);
            }
            __syncthreads();
#pragma unroll
            for (int kk = 0; kk < 32; ++kk) {
                int k = kc * 32 + kk;
                float a[8];
#pragma unroll
                for (int i = 0; i < 8; ++i) a[i] = Xs[ty * 8 + i][k];
                float b[4];
#pragma unroll
                for (int j = 0; j < 4; ++j) b[j] = WL[kk][tx * 4 + j];
#pragma unroll
                for (int i = 0; i < 8; ++i)
#pragma unroll
                    for (int j = 0; j < 4; ++j)
                        acc[i][j] = fmaf(a[i], b[j], acc[i][j]);
            }
        }
        float* O = Oz[w];
#pragma unroll
        for (int i = 0; i < 8; ++i) {
            int row = r0 + ty * 8 + i;
            if (row < N_NODES) {
                float4 v = make_float4(acc[i][0], acc[i][1], acc[i][2], acc[i][3]);
                *(float4*)(O + (size_t)row * DIM + tx * 4) = v;
            }
        }
    }
}

// ---------------------------------------------------------------- aggregation
// One half-wave (32 lanes x float4 = one 512B row) per node. Gathers message
// rows from Xd/Xc per CSR, adds self-term S, applies ReLU. No atomics.
__global__ __launch_bounds__(256) void agg_kernel(
        const int* __restrict__ row_start, const int* __restrict__ cnt,
        const int* __restrict__ col,
        const float* __restrict__ Xd, const float* __restrict__ Xc,
        const float* __restrict__ S, float* __restrict__ Xout) {
    int wave = (blockIdx.x * 256 + threadIdx.x) >> 6;
    int lane = threadIdx.x & 63;
    int half = lane >> 5;
    int l32  = lane & 31;
    int node = wave * 2 + half;
    if (node >= N_NODES) return;

    int rs  = row_start[node];
    int deg = cnt[node];
    float4 acc = make_float4(0.f, 0.f, 0.f, 0.f);

    int e = 0;
    for (; e + 1 < deg; e += 2) {  // 2x unroll: two gathers in flight
        int p0 = col[rs + e];
        int p1 = col[rs + e + 1];
        const float* base0 = ((p0 >> 16) == 0) ? Xd : Xc;
        const float* base1 = ((p1 >> 16) == 0) ? Xd : Xc;
        float4 v0 = *(const float4*)(base0 + (size_t)(p0 & 0xFFFF) * DIM + l32 * 4);
        float4 v1 = *(const float4*)(base1 + (size_t)(p1 & 0xFFFF) * DIM + l32 * 4);
        acc.x += v0.x + v1.x;
        acc.y += v0.y + v1.y;
        acc.z += v0.z + v1.z;
        acc.w += v0.w + v1.w;
    }
    if (e < deg) {
        int p0 = col[rs + e];
        const float* base0 = ((p0 >> 16) == 0) ? Xd : Xc;
        float4 v0 = *(const float4*)(base0 + (size_t)(p0 & 0xFFFF) * DIM + l32 * 4);
        acc.x += v0.x; acc.y += v0.y; acc.z += v0.z; acc.w += v0.w;
    }

    float4 sv = *(const float4*)(S + (size_t)node * DIM + l32 * 4);
    acc.x = fmaxf(acc.x + sv.x, 0.f);
    acc.y = fmaxf(acc.y + sv.y, 0.f);
    acc.z = fmaxf(acc.z + sv.z, 0.f);
    acc.w = fmaxf(acc.w + sv.w, 0.f);
    *(float4*)(Xout + (size_t)node * DIM + l32 * 4) = acc;
}

// ---------------------------------------------------------------- pooling
// batch_ids sorted -> run-length accumulate, flush with one atomic per run.
__global__ __launch_bounds__(256) void pool_kernel(const float* __restrict__ X,
                                                   const int* __restrict__ bid,
                                                   float* __restrict__ sums,
                                                   int* __restrict__ gcnt) {
    int tid = threadIdx.x;
    int h   = tid >> 7;        // 0/1: two interleaved node streams per block
    int d   = tid & 127;       // feature column
    int n0  = blockIdx.x * 256;
    int end = min(n0 + 256, N_NODES);

    float acc = 0.f;
    int cur = -1, run = 0;
    for (int i = n0 + h; i < end; i += 2) {
        int g = bid[i];
        if (g != cur) {
            if (cur >= 0) {
                atomicAdd(&sums[cur * DIM + d], acc);
                if (d == 0) atomicAdd(&gcnt[cur], run);
            }
            acc = 0.f; run = 0; cur = g;
        }
        acc += X[(size_t)i * DIM + d];
        run++;
    }
    if (cur >= 0) {
        atomicAdd(&sums[cur * DIM + d], acc);
        if (d == 0) atomicAdd(&gcnt[cur], run);
    }
}

__global__ __launch_bounds__(256) void div_kernel(const float* __restrict__ sums,
                                                  const int* __restrict__ gcnt,
                                                  float* __restrict__ out) {
    int i = blockIdx.x * 256 + threadIdx.x;
    if (i < NGRAPHS * DIM) {
        int g = i >> 7;
        out[i] = sums[i] / fmaxf((float)gcnt[g], 1.f);
    }
}

// ---------------------------------------------------------------- launcher
extern "C" void kernel_launch(void* const* d_in, const int* in_sizes, int n_in,
                              void* d_out, int out_size, void* d_ws, size_t ws_size,
                              hipStream_t stream) {
    const float* Xin = (const float*)d_in[0];
    const float* Wd  = (const float*)d_in[1];
    const float* bd  = (const float*)d_in[2];
    const float* Wc  = (const float*)d_in[3];
    const float* bc  = (const float*)d_in[4];
    const float* Ws  = (const float*)d_in[5];
    const float* bs  = (const float*)d_in[6];
    const int* edge_index = (const int*)d_in[7];
    const int* edge_types = (const int*)d_in[8];
    const int* batch_ids  = (const int*)d_in[9];

    const int* src = edge_index;            // edge_index[0]
    const int* dst = edge_index + N_EDGES;  // edge_index[1]

    // workspace carve-up (256B aligned regions)
    const size_t NB = (size_t)N_NODES * DIM * sizeof(float);  // 25.6 MB
    char* w = (char*)d_ws;
    auto take = [&](size_t bytes) {
        char* p = w;
        w += (bytes + 255) & ~(size_t)255;
        return p;
    };
    float* Xb0  = (float*)take(NB);
    float* Xb1  = (float*)take(NB);
    float* Xd   = (float*)take(NB);
    float* Xc   = (float*)take(NB);
    float* S    = (float*)take(NB);
    int* col    = (int*)take((size_t)N_EDGES * 4);
    int* cnt    = (int*)take((size_t)N_NODES * 4);
    int* rowst  = (int*)take((size_t)N_NODES * 4);
    int* cursor = (int*)take((size_t)N_NODES * 4);
    int* incl   = (int*)take((size_t)N_NODES * 4);
    int* bsums  = (int*)take(1024);
    float* sums = (float*)take((size_t)NGRAPHS * DIM * 4);
    int* gcnt   = (int*)take(NGRAPHS * 4);

    const int NBLK_N = (N_NODES + 255) / 256;  // 196
    const int NBLK_E = (N_EDGES + 255) / 256;  // 6250

    // zero accumulators (kernels, not memset, to stay capture-safe)
    zero_kernel<<<NBLK_N, 256, 0, stream>>>(cnt, N_NODES);
    zero_kernel<<<(NGRAPHS * DIM + NGRAPHS + 255) / 256 + 1, 256, 0, stream>>>(
        (int*)sums, NGRAPHS * DIM);
    zero_kernel<<<1, 256, 0, stream>>>(gcnt, NGRAPHS);

    // CSR build (edge structure is layer-invariant: build once per call)
    hist_kernel<<<NBLK_E, 256, 0, stream>>>(dst, cnt);
    scan1_kernel<<<NBLK_N, 256, 0, stream>>>(cnt, incl, bsums);
    scan2_kernel<<<1, 256, 0, stream>>>(bsums, NBLK_N);
    scan3_kernel<<<NBLK_N, 256, 0, stream>>>(incl, cnt, bsums, rowst, cursor);
    fill_kernel<<<NBLK_E, 256, 0, stream>>>(src, dst, edge_types, cursor, col);

    // layers
    const int GEMM_BLKS = (N_NODES + 63) / 64;  // 782
    const int AGG_BLKS  = (N_NODES / 2 + 3) / 4;  // 6250 (2 nodes/wave, 4 waves/blk)
    const float* Xcur = Xin;
    float* bufs[3] = {Xb0, Xb1, Xb0};
    for (int l = 0; l < NLAYERS; ++l) {
        gemm3_kernel<<<GEMM_BLKS, 256, 0, stream>>>(
            Xcur,
            Wd + (size_t)l * DIM * DIM, bd + (size_t)l * DIM,
            Wc + (size_t)l * DIM * DIM, bc + (size_t)l * DIM,
            Ws + (size_t)l * DIM * DIM, bs + (size_t)l * DIM,
            Xd, Xc, S);
        float* Xnext = bufs[l];
        agg_kernel<<<AGG_BLKS, 256, 0, stream>>>(rowst, cnt, col, Xd, Xc, S, Xnext);
        Xcur = Xnext;
    }

    // global mean pool
    pool_kernel<<<NBLK_N, 256, 0, stream>>>(Xcur, batch_ids, sums, gcnt);
    div_kernel<<<(NGRAPHS * DIM + 255) / 256, 256, 0, stream>>>(sums, gcnt,
                                                                (float*)d_out);
}

// Round 2
// 958.109 us; speedup vs baseline: 1.0116x; 1.0116x over previous
//
#include <hip/hip_runtime.h>

#define N_NODES 50000
#define N_EDGES 1600000
#define DIM     128
#define NLAYERS 3
#define NGRAPHS 64

// fill/hist batching: 1600000 = 160000 threads * 10 edges
#define EDGE_THREADS 160000
#define EDGE_BATCH   10
#define EDGE_BLOCKS  (EDGE_THREADS / 256)   // 625

// ---------------------------------------------------------------- init
__global__ __launch_bounds__(256) void init_kernel(int* __restrict__ cnt,
                                                   float* __restrict__ sums,
                                                   int* __restrict__ gcnt) {
    int i = blockIdx.x * 256 + threadIdx.x;
    if (i < N_NODES) cnt[i] = 0;
    if (i < NGRAPHS * DIM) sums[i] = 0.f;
    if (i < NGRAPHS) gcnt[i] = 0;
}

// ---------------------------------------------------------------- CSR build
// 10 edges/thread, batched loads -> 10 independent atomic chains in flight
// (R1: 1 edge/thread was latency-bound at 131us, VALUBusy 0.4%).
__global__ __launch_bounds__(256) void hist_kernel(const int* __restrict__ dst,
                                                   int* __restrict__ cnt) {
    int t = blockIdx.x * 256 + threadIdx.x;
    int d[EDGE_BATCH];
#pragma unroll
    for (int i = 0; i < EDGE_BATCH; ++i) d[i] = dst[t + i * EDGE_THREADS];
#pragma unroll
    for (int i = 0; i < EDGE_BATCH; ++i) atomicAdd(&cnt[d[i]], 1);
}

__global__ __launch_bounds__(256) void scan1_kernel(const int* __restrict__ cnt,
                                                    int* __restrict__ incl,
                                                    int* __restrict__ bsums) {
    __shared__ int sh[256];
    int i = blockIdx.x * 256 + threadIdx.x;
    int v = (i < N_NODES) ? cnt[i] : 0;
    sh[threadIdx.x] = v;
    __syncthreads();
    for (int o = 1; o < 256; o <<= 1) {
        int t = (threadIdx.x >= o) ? sh[threadIdx.x - o] : 0;
        __syncthreads();
        sh[threadIdx.x] += t;
        __syncthreads();
    }
    if (i < N_NODES) incl[i] = sh[threadIdx.x];
    if (threadIdx.x == 255) bsums[blockIdx.x] = sh[255];
}

__global__ __launch_bounds__(256) void scan2_kernel(int* __restrict__ bsums, int nb) {
    __shared__ int sh[256];
    int v = (threadIdx.x < nb) ? bsums[threadIdx.x] : 0;
    sh[threadIdx.x] = v;
    __syncthreads();
    for (int o = 1; o < 256; o <<= 1) {
        int t = (threadIdx.x >= o) ? sh[threadIdx.x - o] : 0;
        __syncthreads();
        sh[threadIdx.x] += t;
        __syncthreads();
    }
    if (threadIdx.x < nb) bsums[threadIdx.x] = sh[threadIdx.x] - v;  // exclusive
}

__global__ __launch_bounds__(256) void scan3_kernel(const int* __restrict__ incl,
                                                    const int* __restrict__ cnt,
                                                    const int* __restrict__ bsums,
                                                    int* __restrict__ row_start,
                                                    int* __restrict__ cursor) {
    int i = blockIdx.x * 256 + threadIdx.x;
    if (i < N_NODES) {
        int rs = incl[i] - cnt[i] + bsums[blockIdx.x];
        row_start[i] = rs;
        cursor[i]    = rs;
    }
}

// pack src (<65536) | type<<16; 10 edges/thread for atomic-latency hiding.
__global__ __launch_bounds__(256) void fill_kernel(const int* __restrict__ src,
                                                   const int* __restrict__ dst,
                                                   const int* __restrict__ et,
                                                   int* __restrict__ cursor,
                                                   int* __restrict__ col) {
    int t = blockIdx.x * 256 + threadIdx.x;
    int d[EDGE_BATCH], sv[EDGE_BATCH], p[EDGE_BATCH];
#pragma unroll
    for (int i = 0; i < EDGE_BATCH; ++i) {
        int e = t + i * EDGE_THREADS;
        d[i]  = dst[e];
        sv[i] = src[e] | (et[e] << 16);
    }
#pragma unroll
    for (int i = 0; i < EDGE_BATCH; ++i) p[i] = atomicAdd(&cursor[d[i]], 1);
#pragma unroll
    for (int i = 0; i < EDGE_BATCH; ++i) col[p[i]] = sv[i];
}

// ---------------------------------------------------------------- fused 3-GEMM
// Tile: 64 rows x 128 cols, 256 threads, micro-tile 8x4.
// R2: B-operand read is now ds_read_b128 (was 4x ds_read_b32 with a 4-way
// bank conflict: lanes hit banks (4t+j)%32 = 8 banks x 4 lanes).
__global__ __launch_bounds__(256) void gemm3_kernel(
        const float* __restrict__ X,
        const float* __restrict__ W0, const float* __restrict__ b0,
        const float* __restrict__ W1, const float* __restrict__ b1,
        const float* __restrict__ W2, const float* __restrict__ b2,
        float* __restrict__ O0, float* __restrict__ O1, float* __restrict__ O2) {
    __shared__ float Xs[64][132];
    __shared__ float WL[32][128];

    const int tid = threadIdx.x;
    const int tx  = tid & 31;   // cols tx*4 .. tx*4+3
    const int ty  = tid >> 5;   // rows ty*8 .. ty*8+7
    const int r0  = blockIdx.x * 64;

    {
        const int rr = tid >> 5;
        const int k4 = (tid & 31) * 4;
#pragma unroll
        for (int p = 0; p < 8; ++p) {
            int row  = p * 8 + rr;
            float4 v = make_float4(0.f, 0.f, 0.f, 0.f);
            if (r0 + row < N_NODES)
                v = *(const float4*)(X + (size_t)(r0 + row) * DIM + k4);
            *(float4*)(&Xs[row][k4]) = v;
        }
    }

    const float* Wz[3] = {W0, W1, W2};
    const float* bz[3] = {b0, b1, b2};
    float* Oz[3]       = {O0, O1, O2};

    for (int w = 0; w < 3; ++w) {
        const float* Wg = Wz[w];
        float4 bias     = *(const float4*)(bz[w] + tx * 4);
        float acc[8][4];
#pragma unroll
        for (int i = 0; i < 8; ++i) {
            acc[i][0] = bias.x; acc[i][1] = bias.y;
            acc[i][2] = bias.z; acc[i][3] = bias.w;
        }
        for (int kc = 0; kc < 4; ++kc) {
            __syncthreads();
#pragma unroll
            for (int p = 0; p < 4; ++p) {
                int idx = p * 256 + tid;
                int kk  = idx >> 5;
                int c4  = (idx & 31) * 4;
                *(float4*)(&WL[kk][c4]) =
                    *(const float4*)(Wg + (size_t)(kc * 32 + kk) * DIM + c4);
            }
            __syncthreads();
#pragma unroll
            for (int kk = 0; kk < 32; ++kk) {
                int k = kc * 32 + kk;
                float a[8];
#pragma unroll
                for (int i = 0; i < 8; ++i) a[i] = Xs[ty * 8 + i][k];
                float4 bv = *(const float4*)(&WL[kk][tx * 4]);  // b128, no conflict
#pragma unroll
                for (int i = 0; i < 8; ++i) {
                    acc[i][0] = fmaf(a[i], bv.x, acc[i][0]);
                    acc[i][1] = fmaf(a[i], bv.y, acc[i][1]);
                    acc[i][2] = fmaf(a[i], bv.z, acc[i][2]);
                    acc[i][3] = fmaf(a[i], bv.w, acc[i][3]);
                }
            }
        }
        float* O = Oz[w];
#pragma unroll
        for (int i = 0; i < 8; ++i) {
            int row = r0 + ty * 8 + i;
            if (row < N_NODES) {
                float4 v = make_float4(acc[i][0], acc[i][1], acc[i][2], acc[i][3]);
                *(float4*)(O + (size_t)row * DIM + tx * 4) = v;
            }
        }
    }
}

// ---------------------------------------------------------------- aggregation
// Half-wave (32 lanes x float4) per node; 4-deep unrolled gather with 4
// independent accumulators for memory-level parallelism.
__global__ __launch_bounds__(256) void agg_kernel(
        const int* __restrict__ row_start, const int* __restrict__ cnt,
        const int* __restrict__ col,
        const float* __restrict__ Xd, const float* __restrict__ Xc,
        const float* __restrict__ S, float* __restrict__ Xout) {
    int wave = (blockIdx.x * 256 + threadIdx.x) >> 6;
    int lane = threadIdx.x & 63;
    int half = lane >> 5;
    int l32  = lane & 31;
    int node = wave * 2 + half;
    if (node >= N_NODES) return;

    int rs  = row_start[node];
    int deg = cnt[node];
    float4 a0 = make_float4(0.f, 0.f, 0.f, 0.f);
    float4 a1 = a0, a2 = a0, a3 = a0;
    const size_t off = (size_t)l32 * 4;

    int e = 0;
    for (; e + 4 <= deg; e += 4) {
        int p0 = col[rs + e];
        int p1 = col[rs + e + 1];
        int p2 = col[rs + e + 2];
        int p3 = col[rs + e + 3];
        const float* q0 = (((p0 >> 16) == 0) ? Xd : Xc) + (size_t)(p0 & 0xFFFF) * DIM + off;
        const float* q1 = (((p1 >> 16) == 0) ? Xd : Xc) + (size_t)(p1 & 0xFFFF) * DIM + off;
        const float* q2 = (((p2 >> 16) == 0) ? Xd : Xc) + (size_t)(p2 & 0xFFFF) * DIM + off;
        const float* q3 = (((p3 >> 16) == 0) ? Xd : Xc) + (size_t)(p3 & 0xFFFF) * DIM + off;
        float4 v0 = *(const float4*)q0;
        float4 v1 = *(const float4*)q1;
        float4 v2 = *(const float4*)q2;
        float4 v3 = *(const float4*)q3;
        a0.x += v0.x; a0.y += v0.y; a0.z += v0.z; a0.w += v0.w;
        a1.x += v1.x; a1.y += v1.y; a1.z += v1.z; a1.w += v1.w;
        a2.x += v2.x; a2.y += v2.y; a2.z += v2.z; a2.w += v2.w;
        a3.x += v3.x; a3.y += v3.y; a3.z += v3.w == v3.w ? v3.z : v3.z; a3.w += v3.w;
    }
    for (; e < deg; ++e) {
        int p0 = col[rs + e];
        const float* q0 = (((p0 >> 16) == 0) ? Xd : Xc) + (size_t)(p0 & 0xFFFF) * DIM + off;
        float4 v0 = *(const float4*)q0;
        a0.x += v0.x; a0.y += v0.y; a0.z += v0.z; a0.w += v0.w;
    }

    float4 sv = *(const float4*)(S + (size_t)node * DIM + off);
    float4 r;
    r.x = fmaxf(a0.x + a1.x + a2.x + a3.x + sv.x, 0.f);
    r.y = fmaxf(a0.y + a1.y + a2.y + a3.y + sv.y, 0.f);
    r.z = fmaxf(a0.z + a1.z + a2.z + a3.z + sv.z, 0.f);
    r.w = fmaxf(a0.w + a1.w + a2.w + a3.w + sv.w, 0.f);
    *(float4*)(Xout + (size_t)node * DIM + off) = r;
}

// ---------------------------------------------------------------- pooling
__global__ __launch_bounds__(256) void pool_kernel(const float* __restrict__ X,
                                                   const int* __restrict__ bid,
                                                   float* __restrict__ sums,
                                                   int* __restrict__ gcnt) {
    int tid = threadIdx.x;
    int h   = tid >> 7;
    int d   = tid & 127;
    int n0  = blockIdx.x * 256;
    int end = min(n0 + 256, N_NODES);

    float acc = 0.f;
    int cur = -1, run = 0;
    for (int i = n0 + h; i < end; i += 2) {
        int g = bid[i];
        if (g != cur) {
            if (cur >= 0) {
                atomicAdd(&sums[cur * DIM + d], acc);
                if (d == 0) atomicAdd(&gcnt[cur], run);
            }
            acc = 0.f; run = 0; cur = g;
        }
        acc += X[(size_t)i * DIM + d];
        run++;
    }
    if (cur >= 0) {
        atomicAdd(&sums[cur * DIM + d], acc);
        if (d == 0) atomicAdd(&gcnt[cur], run);
    }
}

__global__ __launch_bounds__(256) void div_kernel(const float* __restrict__ sums,
                                                  const int* __restrict__ gcnt,
                                                  float* __restrict__ out) {
    int i = blockIdx.x * 256 + threadIdx.x;
    if (i < NGRAPHS * DIM) {
        int g = i >> 7;
        out[i] = sums[i] / fmaxf((float)gcnt[g], 1.f);
    }
}

// ---------------------------------------------------------------- launcher
extern "C" void kernel_launch(void* const* d_in, const int* in_sizes, int n_in,
                              void* d_out, int out_size, void* d_ws, size_t ws_size,
                              hipStream_t stream) {
    const float* Xin = (const float*)d_in[0];
    const float* Wd  = (const float*)d_in[1];
    const float* bd  = (const float*)d_in[2];
    const float* Wc  = (const float*)d_in[3];
    const float* bc  = (const float*)d_in[4];
    const float* Ws  = (const float*)d_in[5];
    const float* bs  = (const float*)d_in[6];
    const int* edge_index = (const int*)d_in[7];
    const int* edge_types = (const int*)d_in[8];
    const int* batch_ids  = (const int*)d_in[9];

    const int* src = edge_index;            // edge_index[0]
    const int* dst = edge_index + N_EDGES;  // edge_index[1]

    const size_t NB = (size_t)N_NODES * DIM * sizeof(float);  // 25.6 MB
    char* w = (char*)d_ws;
    auto take = [&](size_t bytes) {
        char* p = w;
        w += (bytes + 255) & ~(size_t)255;
        return p;
    };
    float* Xb0  = (float*)take(NB);
    float* Xb1  = (float*)take(NB);
    float* Xd   = (float*)take(NB);
    float* Xc   = (float*)take(NB);
    float* S    = (float*)take(NB);
    int* col    = (int*)take((size_t)N_EDGES * 4);
    int* cnt    = (int*)take((size_t)N_NODES * 4);
    int* rowst  = (int*)take((size_t)N_NODES * 4);
    int* cursor = (int*)take((size_t)N_NODES * 4);
    int* incl   = (int*)take((size_t)N_NODES * 4);
    int* bsums  = (int*)take(1024);
    float* sums = (float*)take((size_t)NGRAPHS * DIM * 4);
    int* gcnt   = (int*)take(NGRAPHS * 4);

    const int NBLK_N = (N_NODES + 255) / 256;  // 196

    init_kernel<<<NBLK_N, 256, 0, stream>>>(cnt, sums, gcnt);

    hist_kernel<<<EDGE_BLOCKS, 256, 0, stream>>>(dst, cnt);
    scan1_kernel<<<NBLK_N, 256, 0, stream>>>(cnt, incl, bsums);
    scan2_kernel<<<1, 256, 0, stream>>>(bsums, NBLK_N);
    scan3_kernel<<<NBLK_N, 256, 0, stream>>>(incl, cnt, bsums, rowst, cursor);
    fill_kernel<<<EDGE_BLOCKS, 256, 0, stream>>>(src, dst, edge_types, cursor, col);

    const int GEMM_BLKS = (N_NODES + 63) / 64;    // 782
    const int AGG_BLKS  = (N_NODES / 2 + 3) / 4;  // 6250
    const float* Xcur = Xin;
    float* bufs[3] = {Xb0, Xb1, Xb0};
    for (int l = 0; l < NLAYERS; ++l) {
        gemm3_kernel<<<GEMM_BLKS, 256, 0, stream>>>(
            Xcur,
            Wd + (size_t)l * DIM * DIM, bd + (size_t)l * DIM,
            Wc + (size_t)l * DIM * DIM, bc + (size_t)l * DIM,
            Ws + (size_t)l * DIM * DIM, bs + (size_t)l * DIM,
            Xd, Xc, S);
        float* Xnext = bufs[l];
        agg_kernel<<<AGG_BLKS, 256, 0, stream>>>(rowst, cnt, col, Xd, Xc, S, Xnext);
        Xcur = Xnext;
    }

    pool_kernel<<<NBLK_N, 256, 0, stream>>>(Xcur, batch_ids, sums, gcnt);
    div_kernel<<<(NGRAPHS * DIM + 255) / 256, 256, 0, stream>>>(sums, gcnt,
                                                                (float*)d_out);
}

// Round 3
// 880.092 us; speedup vs baseline: 1.1013x; 1.0886x over previous
//
#include <hip/hip_runtime.h>

#define N_NODES 50000
#define N_EDGES 1600000
#define DIM     128
#define NLAYERS 3
#define NGRAPHS 64

// edge kernels: 1600000 = 160000 threads * 10 edges
#define EDGE_THREADS 160000
#define EDGE_BATCH   10
#define EDGE_BLOCKS  (EDGE_THREADS / 256)   // 625

// ---------------------------------------------------------------- init
__global__ __launch_bounds__(256) void init_kernel(int* __restrict__ cnt,
                                                   float* __restrict__ sums,
                                                   int* __restrict__ gcnt) {
    int i = blockIdx.x * 256 + threadIdx.x;
    if (i < N_NODES) cnt[i] = 0;
    if (i < NGRAPHS * DIM) sums[i] = 0.f;
    if (i < NGRAPHS) gcnt[i] = 0;
}

// ---------------------------------------------------------------- CSR build
// hist-rank trick: the atomicAdd return value IS this edge's rank within its
// dst row. Stored sequentially -> fill needs no atomics at all.
__global__ __launch_bounds__(256) void hist_kernel(const int* __restrict__ dst,
                                                   int* __restrict__ cnt,
                                                   int* __restrict__ rank) {
    int t = blockIdx.x * 256 + threadIdx.x;
    int d[EDGE_BATCH], r[EDGE_BATCH];
#pragma unroll
    for (int i = 0; i < EDGE_BATCH; ++i) d[i] = dst[t + i * EDGE_THREADS];
#pragma unroll
    for (int i = 0; i < EDGE_BATCH; ++i) r[i] = atomicAdd(&cnt[d[i]], 1);
#pragma unroll
    for (int i = 0; i < EDGE_BATCH; ++i) rank[t + i * EDGE_THREADS] = r[i];
}

__global__ __launch_bounds__(256) void scan1_kernel(const int* __restrict__ cnt,
                                                    int* __restrict__ incl,
                                                    int* __restrict__ bsums) {
    __shared__ int sh[256];
    int i = blockIdx.x * 256 + threadIdx.x;
    int v = (i < N_NODES) ? cnt[i] : 0;
    sh[threadIdx.x] = v;
    __syncthreads();
    for (int o = 1; o < 256; o <<= 1) {
        int t = (threadIdx.x >= o) ? sh[threadIdx.x - o] : 0;
        __syncthreads();
        sh[threadIdx.x] += t;
        __syncthreads();
    }
    if (i < N_NODES) incl[i] = sh[threadIdx.x];
    if (threadIdx.x == 255) bsums[blockIdx.x] = sh[255];
}

__global__ __launch_bounds__(256) void scan2_kernel(int* __restrict__ bsums, int nb) {
    __shared__ int sh[256];
    int v = (threadIdx.x < nb) ? bsums[threadIdx.x] : 0;
    sh[threadIdx.x] = v;
    __syncthreads();
    for (int o = 1; o < 256; o <<= 1) {
        int t = (threadIdx.x >= o) ? sh[threadIdx.x - o] : 0;
        __syncthreads();
        sh[threadIdx.x] += t;
        __syncthreads();
    }
    if (threadIdx.x < nb) bsums[threadIdx.x] = sh[threadIdx.x] - v;  // exclusive
}

__global__ __launch_bounds__(256) void scan3_kernel(const int* __restrict__ incl,
                                                    const int* __restrict__ cnt,
                                                    const int* __restrict__ bsums,
                                                    int* __restrict__ row_start) {
    int i = blockIdx.x * 256 + threadIdx.x;
    if (i < N_NODES)
        row_start[i] = incl[i] - cnt[i] + bsums[blockIdx.x];
}

// pack src (<65536) | type<<16. No atomics: pos = row_start[dst] + rank.
__global__ __launch_bounds__(256) void fill_kernel(const int* __restrict__ src,
                                                   const int* __restrict__ dst,
                                                   const int* __restrict__ et,
                                                   const int* __restrict__ rank,
                                                   const int* __restrict__ rowst,
                                                   int* __restrict__ col) {
    int t = blockIdx.x * 256 + threadIdx.x;
    int d[EDGE_BATCH], sv[EDGE_BATCH], rk[EDGE_BATCH], p[EDGE_BATCH];
#pragma unroll
    for (int i = 0; i < EDGE_BATCH; ++i) {
        int e = t + i * EDGE_THREADS;
        d[i]  = dst[e];
        rk[i] = rank[e];
        sv[i] = src[e] | (et[e] << 16);
    }
#pragma unroll
    for (int i = 0; i < EDGE_BATCH; ++i) p[i] = rowst[d[i]] + rk[i];
#pragma unroll
    for (int i = 0; i < EDGE_BATCH; ++i) col[p[i]] = sv[i];
}

// ---------------------------------------------------------------- fused 3-GEMM
// Tile: 64 rows x 128 cols, 256 threads, micro-tile 8 rows x 4 cols.
// R3: k processed in quads -> A-operand via ds_read_b128 (8 b128 per 4
// k-steps = 24 cyc/step) instead of 8 ds_read_b32 per step (46 cyc/step).
// LDS pipe drops below VALU pipe -> FMA-bound.
__global__ __launch_bounds__(256) void gemm3_kernel(
        const float* __restrict__ X,
        const float* __restrict__ W0, const float* __restrict__ b0,
        const float* __restrict__ W1, const float* __restrict__ b1,
        const float* __restrict__ W2, const float* __restrict__ b2,
        float* __restrict__ O0, float* __restrict__ O1, float* __restrict__ O2) {
    __shared__ float Xs[64][132];   // +4 pad keeps b128 16B-aligned, rows offset
    __shared__ float WL[32][128];

    const int tid = threadIdx.x;
    const int tx  = tid & 31;   // cols tx*4 .. tx*4+3
    const int ty  = tid >> 5;   // rows ty*8 .. ty*8+7
    const int r0  = blockIdx.x * 64;

    {
        const int rr = tid >> 5;
        const int k4 = (tid & 31) * 4;
#pragma unroll
        for (int p = 0; p < 8; ++p) {
            int row  = p * 8 + rr;
            float4 v = make_float4(0.f, 0.f, 0.f, 0.f);
            if (r0 + row < N_NODES)
                v = *(const float4*)(X + (size_t)(r0 + row) * DIM + k4);
            *(float4*)(&Xs[row][k4]) = v;
        }
    }

    const float* Wz[3] = {W0, W1, W2};
    const float* bz[3] = {b0, b1, b2};
    float* Oz[3]       = {O0, O1, O2};

    for (int w = 0; w < 3; ++w) {
        const float* Wg = Wz[w];
        float4 bias     = *(const float4*)(bz[w] + tx * 4);
        float acc[8][4];
#pragma unroll
        for (int i = 0; i < 8; ++i) {
            acc[i][0] = bias.x; acc[i][1] = bias.y;
            acc[i][2] = bias.z; acc[i][3] = bias.w;
        }
        for (int kc = 0; kc < 4; ++kc) {
            __syncthreads();
#pragma unroll
            for (int p = 0; p < 4; ++p) {
                int idx = p * 256 + tid;
                int kk  = idx >> 5;
                int c4  = (idx & 31) * 4;
                *(float4*)(&WL[kk][c4]) =
                    *(const float4*)(Wg + (size_t)(kc * 32 + kk) * DIM + c4);
            }
            __syncthreads();
#pragma unroll
            for (int kq = 0; kq < 8; ++kq) {
                float4 av[8];
#pragma unroll
                for (int i = 0; i < 8; ++i)
                    av[i] = *(const float4*)(&Xs[ty * 8 + i][kc * 32 + kq * 4]);
                float4 bv[4];
#pragma unroll
                for (int j = 0; j < 4; ++j)
                    bv[j] = *(const float4*)(&WL[kq * 4 + j][tx * 4]);
#pragma unroll
                for (int i = 0; i < 8; ++i) {
                    acc[i][0] = fmaf(av[i].x, bv[0].x, acc[i][0]);
                    acc[i][1] = fmaf(av[i].x, bv[0].y, acc[i][1]);
                    acc[i][2] = fmaf(av[i].x, bv[0].z, acc[i][2]);
                    acc[i][3] = fmaf(av[i].x, bv[0].w, acc[i][3]);
                    acc[i][0] = fmaf(av[i].y, bv[1].x, acc[i][0]);
                    acc[i][1] = fmaf(av[i].y, bv[1].y, acc[i][1]);
                    acc[i][2] = fmaf(av[i].y, bv[1].z, acc[i][2]);
                    acc[i][3] = fmaf(av[i].y, bv[1].w, acc[i][3]);
                    acc[i][0] = fmaf(av[i].z, bv[2].x, acc[i][0]);
                    acc[i][1] = fmaf(av[i].z, bv[2].y, acc[i][1]);
                    acc[i][2] = fmaf(av[i].z, bv[2].z, acc[i][2]);
                    acc[i][3] = fmaf(av[i].z, bv[2].w, acc[i][3]);
                    acc[i][0] = fmaf(av[i].w, bv[3].x, acc[i][0]);
                    acc[i][1] = fmaf(av[i].w, bv[3].y, acc[i][1]);
                    acc[i][2] = fmaf(av[i].w, bv[3].z, acc[i][2]);
                    acc[i][3] = fmaf(av[i].w, bv[3].w, acc[i][3]);
                }
            }
        }
        float* O = Oz[w];
#pragma unroll
        for (int i = 0; i < 8; ++i) {
            int row = r0 + ty * 8 + i;
            if (row < N_NODES) {
                float4 v = make_float4(acc[i][0], acc[i][1], acc[i][2], acc[i][3]);
                *(float4*)(O + (size_t)row * DIM + tx * 4) = v;
            }
        }
    }
}

// ---------------------------------------------------------------- aggregation
// Half-wave (32 lanes x float4) per node; 8-deep unrolled gather, 8
// independent accumulators (R3: was 4 -> probe latency- vs BW-bound).
__global__ __launch_bounds__(256) void agg_kernel(
        const int* __restrict__ row_start, const int* __restrict__ cnt,
        const int* __restrict__ col,
        const float* __restrict__ Xd, const float* __restrict__ Xc,
        const float* __restrict__ S, float* __restrict__ Xout) {
    int wave = (blockIdx.x * 256 + threadIdx.x) >> 6;
    int lane = threadIdx.x & 63;
    int half = lane >> 5;
    int l32  = lane & 31;
    int node = wave * 2 + half;
    if (node >= N_NODES) return;

    int rs  = row_start[node];
    int deg = cnt[node];
    const size_t off = (size_t)l32 * 4;

    float4 a[8];
#pragma unroll
    for (int i = 0; i < 8; ++i) a[i] = make_float4(0.f, 0.f, 0.f, 0.f);

    int e = 0;
    for (; e + 8 <= deg; e += 8) {
        int p[8];
#pragma unroll
        for (int i = 0; i < 8; ++i) p[i] = col[rs + e + i];
        float4 v[8];
#pragma unroll
        for (int i = 0; i < 8; ++i) {
            const float* q = (((p[i] >> 16) == 0) ? Xd : Xc)
                             + (size_t)(p[i] & 0xFFFF) * DIM + off;
            v[i] = *(const float4*)q;
        }
#pragma unroll
        for (int i = 0; i < 8; ++i) {
            a[i].x += v[i].x; a[i].y += v[i].y;
            a[i].z += v[i].z; a[i].w += v[i].w;
        }
    }
    for (; e < deg; ++e) {
        int p0 = col[rs + e];
        const float* q = (((p0 >> 16) == 0) ? Xd : Xc)
                         + (size_t)(p0 & 0xFFFF) * DIM + off;
        float4 v0 = *(const float4*)q;
        a[0].x += v0.x; a[0].y += v0.y; a[0].z += v0.z; a[0].w += v0.w;
    }

#pragma unroll
    for (int i = 1; i < 8; ++i) {
        a[0].x += a[i].x; a[0].y += a[i].y;
        a[0].z += a[i].z; a[0].w += a[i].w;
    }

    float4 sv = *(const float4*)(S + (size_t)node * DIM + off);
    float4 r;
    r.x = fmaxf(a[0].x + sv.x, 0.f);
    r.y = fmaxf(a[0].y + sv.y, 0.f);
    r.z = fmaxf(a[0].z + sv.z, 0.f);
    r.w = fmaxf(a[0].w + sv.w, 0.f);
    *(float4*)(Xout + (size_t)node * DIM + off) = r;
}

// ---------------------------------------------------------------- pooling
__global__ __launch_bounds__(256) void pool_kernel(const float* __restrict__ X,
                                                   const int* __restrict__ bid,
                                                   float* __restrict__ sums,
                                                   int* __restrict__ gcnt) {
    int tid = threadIdx.x;
    int h   = tid >> 7;
    int d   = tid & 127;
    int n0  = blockIdx.x * 256;
    int end = min(n0 + 256, N_NODES);

    float acc = 0.f;
    int cur = -1, run = 0;
    for (int i = n0 + h; i < end; i += 2) {
        int g = bid[i];
        if (g != cur) {
            if (cur >= 0) {
                atomicAdd(&sums[cur * DIM + d], acc);
                if (d == 0) atomicAdd(&gcnt[cur], run);
            }
            acc = 0.f; run = 0; cur = g;
        }
        acc += X[(size_t)i * DIM + d];
        run++;
    }
    if (cur >= 0) {
        atomicAdd(&sums[cur * DIM + d], acc);
        if (d == 0) atomicAdd(&gcnt[cur], run);
    }
}

__global__ __launch_bounds__(256) void div_kernel(const float* __restrict__ sums,
                                                  const int* __restrict__ gcnt,
                                                  float* __restrict__ out) {
    int i = blockIdx.x * 256 + threadIdx.x;
    if (i < NGRAPHS * DIM) {
        int g = i >> 7;
        out[i] = sums[i] / fmaxf((float)gcnt[g], 1.f);
    }
}

// ---------------------------------------------------------------- launcher
extern "C" void kernel_launch(void* const* d_in, const int* in_sizes, int n_in,
                              void* d_out, int out_size, void* d_ws, size_t ws_size,
                              hipStream_t stream) {
    const float* Xin = (const float*)d_in[0];
    const float* Wd  = (const float*)d_in[1];
    const float* bd  = (const float*)d_in[2];
    const float* Wc  = (const float*)d_in[3];
    const float* bc  = (const float*)d_in[4];
    const float* Ws  = (const float*)d_in[5];
    const float* bs  = (const float*)d_in[6];
    const int* edge_index = (const int*)d_in[7];
    const int* edge_types = (const int*)d_in[8];
    const int* batch_ids  = (const int*)d_in[9];

    const int* src = edge_index;            // edge_index[0]
    const int* dst = edge_index + N_EDGES;  // edge_index[1]

    const size_t NB = (size_t)N_NODES * DIM * sizeof(float);  // 25.6 MB
    char* w = (char*)d_ws;
    auto take = [&](size_t bytes) {
        char* p = w;
        w += (bytes + 255) & ~(size_t)255;
        return p;
    };
    float* Xb0  = (float*)take(NB);
    float* Xb1  = (float*)take(NB);
    float* Xd   = (float*)take(NB);
    float* Xc   = (float*)take(NB);
    float* S    = (float*)take(NB);
    int* col    = (int*)take((size_t)N_EDGES * 4);
    int* rank   = (int*)take((size_t)N_EDGES * 4);
    int* cnt    = (int*)take((size_t)N_NODES * 4);
    int* rowst  = (int*)take((size_t)N_NODES * 4);
    int* incl   = (int*)take((size_t)N_NODES * 4);
    int* bsums  = (int*)take(1024);
    float* sums = (float*)take((size_t)NGRAPHS * DIM * 4);
    int* gcnt   = (int*)take(NGRAPHS * 4);

    const int NBLK_N = (N_NODES + 255) / 256;  // 196

    init_kernel<<<NBLK_N, 256, 0, stream>>>(cnt, sums, gcnt);

    hist_kernel<<<EDGE_BLOCKS, 256, 0, stream>>>(dst, cnt, rank);
    scan1_kernel<<<NBLK_N, 256, 0, stream>>>(cnt, incl, bsums);
    scan2_kernel<<<1, 256, 0, stream>>>(bsums, NBLK_N);
    scan3_kernel<<<NBLK_N, 256, 0, stream>>>(incl, cnt, bsums, rowst);
    fill_kernel<<<EDGE_BLOCKS, 256, 0, stream>>>(src, dst, edge_types, rank,
                                                 rowst, col);

    const int GEMM_BLKS = (N_NODES + 63) / 64;    // 782
    const int AGG_BLKS  = (N_NODES / 2 + 3) / 4;  // 6250
    const float* Xcur = Xin;
    float* bufs[3] = {Xb0, Xb1, Xb0};
    for (int l = 0; l < NLAYERS; ++l) {
        gemm3_kernel<<<GEMM_BLKS, 256, 0, stream>>>(
            Xcur,
            Wd + (size_t)l * DIM * DIM, bd + (size_t)l * DIM,
            Wc + (size_t)l * DIM * DIM, bc + (size_t)l * DIM,
            Ws + (size_t)l * DIM * DIM, bs + (size_t)l * DIM,
            Xd, Xc, S);
        float* Xnext = bufs[l];
        agg_kernel<<<AGG_BLKS, 256, 0, stream>>>(rowst, cnt, col, Xd, Xc, S, Xnext);
        Xcur = Xnext;
    }

    pool_kernel<<<NBLK_N, 256, 0, stream>>>(Xcur, batch_ids, sums, gcnt);
    div_kernel<<<(NGRAPHS * DIM + 255) / 256, 256, 0, stream>>>(sums, gcnt,
                                                                (float*)d_out);
}

// Round 4
// 700.807 us; speedup vs baseline: 1.3830x; 1.2558x over previous
//
#include <hip/hip_runtime.h>
#include <hip/hip_fp16.h>

#define N_NODES 50000
#define N_EDGES 1600000
#define DIM     128
#define NLAYERS 3
#define NGRAPHS 64

// edge kernels: 1600000 = 160000 threads * 10 edges
#define EDGE_THREADS 160000
#define EDGE_BATCH   10
#define EDGE_BLOCKS  (EDGE_THREADS / 256)   // 625

// ---------------------------------------------------------------- init
__global__ __launch_bounds__(256) void init_kernel(int* __restrict__ cnt,
                                                   float* __restrict__ sums,
                                                   int* __restrict__ gcnt) {
    int i = blockIdx.x * 256 + threadIdx.x;
    if (i < N_NODES) cnt[i] = 0;
    if (i < NGRAPHS * DIM) sums[i] = 0.f;
    if (i < NGRAPHS) gcnt[i] = 0;
}

// ---------------------------------------------------------------- CSR build
// hist-rank trick: atomicAdd return value IS the edge's rank within its dst
// row; stored sequentially -> fill needs no atomics.
__global__ __launch_bounds__(256) void hist_kernel(const int* __restrict__ dst,
                                                   int* __restrict__ cnt,
                                                   int* __restrict__ rank) {
    int t = blockIdx.x * 256 + threadIdx.x;
    int d[EDGE_BATCH], r[EDGE_BATCH];
#pragma unroll
    for (int i = 0; i < EDGE_BATCH; ++i) d[i] = dst[t + i * EDGE_THREADS];
#pragma unroll
    for (int i = 0; i < EDGE_BATCH; ++i) r[i] = atomicAdd(&cnt[d[i]], 1);
#pragma unroll
    for (int i = 0; i < EDGE_BATCH; ++i) rank[t + i * EDGE_THREADS] = r[i];
}

__global__ __launch_bounds__(256) void scan1_kernel(const int* __restrict__ cnt,
                                                    int* __restrict__ incl,
                                                    int* __restrict__ bsums) {
    __shared__ int sh[256];
    int i = blockIdx.x * 256 + threadIdx.x;
    int v = (i < N_NODES) ? cnt[i] : 0;
    sh[threadIdx.x] = v;
    __syncthreads();
    for (int o = 1; o < 256; o <<= 1) {
        int t = (threadIdx.x >= o) ? sh[threadIdx.x - o] : 0;
        __syncthreads();
        sh[threadIdx.x] += t;
        __syncthreads();
    }
    if (i < N_NODES) incl[i] = sh[threadIdx.x];
    if (threadIdx.x == 255) bsums[blockIdx.x] = sh[255];
}

__global__ __launch_bounds__(256) void scan2_kernel(int* __restrict__ bsums, int nb) {
    __shared__ int sh[256];
    int v = (threadIdx.x < nb) ? bsums[threadIdx.x] : 0;
    sh[threadIdx.x] = v;
    __syncthreads();
    for (int o = 1; o < 256; o <<= 1) {
        int t = (threadIdx.x >= o) ? sh[threadIdx.x - o] : 0;
        __syncthreads();
        sh[threadIdx.x] += t;
        __syncthreads();
    }
    if (threadIdx.x < nb) bsums[threadIdx.x] = sh[threadIdx.x] - v;  // exclusive
}

__global__ __launch_bounds__(256) void scan3_kernel(const int* __restrict__ incl,
                                                    const int* __restrict__ cnt,
                                                    const int* __restrict__ bsums,
                                                    int* __restrict__ row_start) {
    int i = blockIdx.x * 256 + threadIdx.x;
    if (i < N_NODES)
        row_start[i] = incl[i] - cnt[i] + bsums[blockIdx.x];
}

// col packs (type*N + src): direct row index into the fp16 Xdc buffer
// (Xd rows 0..N, Xc rows N..2N) -> no select/mask in agg's hot loop.
__global__ __launch_bounds__(256) void fill_kernel(const int* __restrict__ src,
                                                   const int* __restrict__ dst,
                                                   const int* __restrict__ et,
                                                   const int* __restrict__ rank,
                                                   const int* __restrict__ rowst,
                                                   int* __restrict__ col) {
    int t = blockIdx.x * 256 + threadIdx.x;
    int d[EDGE_BATCH], sv[EDGE_BATCH], rk[EDGE_BATCH], p[EDGE_BATCH];
#pragma unroll
    for (int i = 0; i < EDGE_BATCH; ++i) {
        int e = t + i * EDGE_THREADS;
        d[i]  = dst[e];
        rk[i] = rank[e];
        sv[i] = src[e] + et[e] * N_NODES;
    }
#pragma unroll
    for (int i = 0; i < EDGE_BATCH; ++i) p[i] = rowst[d[i]] + rk[i];
#pragma unroll
    for (int i = 0; i < EDGE_BATCH; ++i) col[p[i]] = sv[i];
}

// ---------------------------------------------------------------- fused 3-GEMM
// Tile: 64 rows x 128 cols, 256 threads, micro-tile 8x4, k in quads
// (ds_read_b128 A-operand). R4: Xd/Xc outputs stored as fp16 (halves the
// agg gather bytes); S (self term) stays fp32.
__global__ __launch_bounds__(256) void gemm3_kernel(
        const float* __restrict__ X,
        const float* __restrict__ W0, const float* __restrict__ b0,
        const float* __restrict__ W1, const float* __restrict__ b1,
        const float* __restrict__ W2, const float* __restrict__ b2,
        __half* __restrict__ Od, __half* __restrict__ Oc,
        float* __restrict__ Os) {
    __shared__ float Xs[64][132];
    __shared__ float WL[32][128];

    const int tid = threadIdx.x;
    const int tx  = tid & 31;
    const int ty  = tid >> 5;
    const int r0  = blockIdx.x * 64;

    {
        const int rr = tid >> 5;
        const int k4 = (tid & 31) * 4;
#pragma unroll
        for (int p = 0; p < 8; ++p) {
            int row  = p * 8 + rr;
            float4 v = make_float4(0.f, 0.f, 0.f, 0.f);
            if (r0 + row < N_NODES)
                v = *(const float4*)(X + (size_t)(r0 + row) * DIM + k4);
            *(float4*)(&Xs[row][k4]) = v;
        }
    }

    const float* Wz[3] = {W0, W1, W2};
    const float* bz[3] = {b0, b1, b2};
    __half* Oh[2]      = {Od, Oc};

    for (int w = 0; w < 3; ++w) {
        const float* Wg = Wz[w];
        float4 bias     = *(const float4*)(bz[w] + tx * 4);
        float acc[8][4];
#pragma unroll
        for (int i = 0; i < 8; ++i) {
            acc[i][0] = bias.x; acc[i][1] = bias.y;
            acc[i][2] = bias.z; acc[i][3] = bias.w;
        }
        for (int kc = 0; kc < 4; ++kc) {
            __syncthreads();
#pragma unroll
            for (int p = 0; p < 4; ++p) {
                int idx = p * 256 + tid;
                int kk  = idx >> 5;
                int c4  = (idx & 31) * 4;
                *(float4*)(&WL[kk][c4]) =
                    *(const float4*)(Wg + (size_t)(kc * 32 + kk) * DIM + c4);
            }
            __syncthreads();
#pragma unroll
            for (int kq = 0; kq < 8; ++kq) {
                float4 av[8];
#pragma unroll
                for (int i = 0; i < 8; ++i)
                    av[i] = *(const float4*)(&Xs[ty * 8 + i][kc * 32 + kq * 4]);
                float4 bv[4];
#pragma unroll
                for (int j = 0; j < 4; ++j)
                    bv[j] = *(const float4*)(&WL[kq * 4 + j][tx * 4]);
#pragma unroll
                for (int i = 0; i < 8; ++i) {
                    acc[i][0] = fmaf(av[i].x, bv[0].x, acc[i][0]);
                    acc[i][1] = fmaf(av[i].x, bv[0].y, acc[i][1]);
                    acc[i][2] = fmaf(av[i].x, bv[0].z, acc[i][2]);
                    acc[i][3] = fmaf(av[i].x, bv[0].w, acc[i][3]);
                    acc[i][0] = fmaf(av[i].y, bv[1].x, acc[i][0]);
                    acc[i][1] = fmaf(av[i].y, bv[1].y, acc[i][1]);
                    acc[i][2] = fmaf(av[i].y, bv[1].z, acc[i][2]);
                    acc[i][3] = fmaf(av[i].y, bv[1].w, acc[i][3]);
                    acc[i][0] = fmaf(av[i].z, bv[2].x, acc[i][0]);
                    acc[i][1] = fmaf(av[i].z, bv[2].y, acc[i][1]);
                    acc[i][2] = fmaf(av[i].z, bv[2].z, acc[i][2]);
                    acc[i][3] = fmaf(av[i].z, bv[2].w, acc[i][3]);
                    acc[i][0] = fmaf(av[i].w, bv[3].x, acc[i][0]);
                    acc[i][1] = fmaf(av[i].w, bv[3].y, acc[i][1]);
                    acc[i][2] = fmaf(av[i].w, bv[3].z, acc[i][2]);
                    acc[i][3] = fmaf(av[i].w, bv[3].w, acc[i][3]);
                }
            }
        }
        if (w < 2) {
            __half* O = Oh[w];
#pragma unroll
            for (int i = 0; i < 8; ++i) {
                int row = r0 + ty * 8 + i;
                if (row < N_NODES) {
                    union { __half2 h2[2]; uint2 u; } pk;
                    pk.h2[0] = __floats2half2_rn(acc[i][0], acc[i][1]);
                    pk.h2[1] = __floats2half2_rn(acc[i][2], acc[i][3]);
                    *(uint2*)(O + (size_t)row * DIM + tx * 4) = pk.u;
                }
            }
        } else {
#pragma unroll
            for (int i = 0; i < 8; ++i) {
                int row = r0 + ty * 8 + i;
                if (row < N_NODES) {
                    float4 v = make_float4(acc[i][0], acc[i][1],
                                           acc[i][2], acc[i][3]);
                    *(float4*)(Os + (size_t)row * DIM + tx * 4) = v;
                }
            }
        }
    }
}

// ---------------------------------------------------------------- aggregation
// Half-wave (32 lanes) per node, fp16 message rows (256 B): lane loads
// uint2 = 4 halves, converts, accumulates fp32. 8-deep unrolled gather.
__global__ __launch_bounds__(256) void agg_kernel(
        const int* __restrict__ row_start, const int* __restrict__ cnt,
        const int* __restrict__ col,
        const __half* __restrict__ Xdc,
        const float* __restrict__ S, float* __restrict__ Xout) {
    int wave = (blockIdx.x * 256 + threadIdx.x) >> 6;
    int lane = threadIdx.x & 63;
    int half = lane >> 5;
    int l32  = lane & 31;
    int node = wave * 2 + half;
    if (node >= N_NODES) return;

    int rs  = row_start[node];
    int deg = cnt[node];
    const size_t off = (size_t)l32 * 4;   // in halves

    float4 a[8];
#pragma unroll
    for (int i = 0; i < 8; ++i) a[i] = make_float4(0.f, 0.f, 0.f, 0.f);

    int e = 0;
    for (; e + 8 <= deg; e += 8) {
        int p[8];
#pragma unroll
        for (int i = 0; i < 8; ++i) p[i] = col[rs + e + i];
        union { uint2 u; __half2 h2[2]; } v[8];
#pragma unroll
        for (int i = 0; i < 8; ++i)
            v[i].u = *(const uint2*)(Xdc + (size_t)p[i] * DIM + off);
#pragma unroll
        for (int i = 0; i < 8; ++i) {
            float2 f0 = __half22float2(v[i].h2[0]);
            float2 f1 = __half22float2(v[i].h2[1]);
            a[i].x += f0.x; a[i].y += f0.y;
            a[i].z += f1.x; a[i].w += f1.y;
        }
    }
    for (; e < deg; ++e) {
        int p0 = col[rs + e];
        union { uint2 u; __half2 h2[2]; } v0;
        v0.u = *(const uint2*)(Xdc + (size_t)p0 * DIM + off);
        float2 f0 = __half22float2(v0.h2[0]);
        float2 f1 = __half22float2(v0.h2[1]);
        a[0].x += f0.x; a[0].y += f0.y;
        a[0].z += f1.x; a[0].w += f1.y;
    }

#pragma unroll
    for (int i = 1; i < 8; ++i) {
        a[0].x += a[i].x; a[0].y += a[i].y;
        a[0].z += a[i].z; a[0].w += a[i].w;
    }

    float4 sv = *(const float4*)(S + (size_t)node * DIM + off);
    float4 r;
    r.x = fmaxf(a[0].x + sv.x, 0.f);
    r.y = fmaxf(a[0].y + sv.y, 0.f);
    r.z = fmaxf(a[0].z + sv.z, 0.f);
    r.w = fmaxf(a[0].w + sv.w, 0.f);
    *(float4*)(Xout + (size_t)node * DIM + off) = r;
}

// ---------------------------------------------------------------- pooling
__global__ __launch_bounds__(256) void pool_kernel(const float* __restrict__ X,
                                                   const int* __restrict__ bid,
                                                   float* __restrict__ sums,
                                                   int* __restrict__ gcnt) {
    int tid = threadIdx.x;
    int h   = tid >> 7;
    int d   = tid & 127;
    int n0  = blockIdx.x * 256;
    int end = min(n0 + 256, N_NODES);

    float acc = 0.f;
    int cur = -1, run = 0;
    for (int i = n0 + h; i < end; i += 2) {
        int g = bid[i];
        if (g != cur) {
            if (cur >= 0) {
                atomicAdd(&sums[cur * DIM + d], acc);
                if (d == 0) atomicAdd(&gcnt[cur], run);
            }
            acc = 0.f; run = 0; cur = g;
        }
        acc += X[(size_t)i * DIM + d];
        run++;
    }
    if (cur >= 0) {
        atomicAdd(&sums[cur * DIM + d], acc);
        if (d == 0) atomicAdd(&gcnt[cur], run);
    }
}

__global__ __launch_bounds__(256) void div_kernel(const float* __restrict__ sums,
                                                  const int* __restrict__ gcnt,
                                                  float* __restrict__ out) {
    int i = blockIdx.x * 256 + threadIdx.x;
    if (i < NGRAPHS * DIM) {
        int g = i >> 7;
        out[i] = sums[i] / fmaxf((float)gcnt[g], 1.f);
    }
}

// ---------------------------------------------------------------- launcher
extern "C" void kernel_launch(void* const* d_in, const int* in_sizes, int n_in,
                              void* d_out, int out_size, void* d_ws, size_t ws_size,
                              hipStream_t stream) {
    const float* Xin = (const float*)d_in[0];
    const float* Wd  = (const float*)d_in[1];
    const float* bd  = (const float*)d_in[2];
    const float* Wc  = (const float*)d_in[3];
    const float* bc  = (const float*)d_in[4];
    const float* Ws  = (const float*)d_in[5];
    const float* bs  = (const float*)d_in[6];
    const int* edge_index = (const int*)d_in[7];
    const int* edge_types = (const int*)d_in[8];
    const int* batch_ids  = (const int*)d_in[9];

    const int* src = edge_index;
    const int* dst = edge_index + N_EDGES;

    const size_t NB  = (size_t)N_NODES * DIM * sizeof(float);   // 25.6 MB
    const size_t NBH = (size_t)N_NODES * DIM * sizeof(__half);  // 12.8 MB
    char* w = (char*)d_ws;
    auto take = [&](size_t bytes) {
        char* p = w;
        w += (bytes + 255) & ~(size_t)255;
        return p;
    };
    float* Xb0   = (float*)take(NB);
    float* Xb1   = (float*)take(NB);
    __half* Xdc  = (__half*)take(2 * NBH);  // rows 0..N = Xd, N..2N = Xc
    float* S     = (float*)take(NB);
    int* col     = (int*)take((size_t)N_EDGES * 4);
    int* rank    = (int*)take((size_t)N_EDGES * 4);
    int* cnt     = (int*)take((size_t)N_NODES * 4);
    int* rowst   = (int*)take((size_t)N_NODES * 4);
    int* incl    = (int*)take((size_t)N_NODES * 4);
    int* bsums   = (int*)take(1024);
    float* sums  = (float*)take((size_t)NGRAPHS * DIM * 4);
    int* gcnt    = (int*)take(NGRAPHS * 4);

    const int NBLK_N = (N_NODES + 255) / 256;  // 196

    init_kernel<<<NBLK_N, 256, 0, stream>>>(cnt, sums, gcnt);

    hist_kernel<<<EDGE_BLOCKS, 256, 0, stream>>>(dst, cnt, rank);
    scan1_kernel<<<NBLK_N, 256, 0, stream>>>(cnt, incl, bsums);
    scan2_kernel<<<1, 256, 0, stream>>>(bsums, NBLK_N);
    scan3_kernel<<<NBLK_N, 256, 0, stream>>>(incl, cnt, bsums, rowst);
    fill_kernel<<<EDGE_BLOCKS, 256, 0, stream>>>(src, dst, edge_types, rank,
                                                 rowst, col);

    const int GEMM_BLKS = (N_NODES + 63) / 64;    // 782
    const int AGG_BLKS  = (N_NODES / 2 + 3) / 4;  // 6250
    const float* Xcur = Xin;
    float* bufs[3] = {Xb0, Xb1, Xb0};
    for (int l = 0; l < NLAYERS; ++l) {
        gemm3_kernel<<<GEMM_BLKS, 256, 0, stream>>>(
            Xcur,
            Wd + (size_t)l * DIM * DIM, bd + (size_t)l * DIM,
            Wc + (size_t)l * DIM * DIM, bc + (size_t)l * DIM,
            Ws + (size_t)l * DIM * DIM, bs + (size_t)l * DIM,
            Xdc, Xdc + (size_t)N_NODES * DIM, S);
        float* Xnext = bufs[l];
        agg_kernel<<<AGG_BLKS, 256, 0, stream>>>(rowst, cnt, col, Xdc, S, Xnext);
        Xcur = Xnext;
    }

    pool_kernel<<<NBLK_N, 256, 0, stream>>>(Xcur, batch_ids, sums, gcnt);
    div_kernel<<<(NGRAPHS * DIM + 255) / 256, 256, 0, stream>>>(sums, gcnt,
                                                                (float*)d_out);
}

// Round 6
// 492.079 us; speedup vs baseline: 1.9696x; 1.4242x over previous
//
#include <hip/hip_runtime.h>
#include <hip/hip_fp16.h>

#define N_NODES 50000
#define N_EDGES 1600000
#define DIM     128
#define NLAYERS 3
#define NGRAPHS 64

// edge kernels: 1600000 = 160000 threads * 10 edges
#define EDGE_THREADS 160000
#define EDGE_BATCH   10
#define EDGE_BLOCKS  (EDGE_THREADS / 256)   // 625

typedef _Float16 half8 __attribute__((ext_vector_type(8)));
typedef float    f32x4 __attribute__((ext_vector_type(4)));

#define LDK 136   // padded halves/row: 272B stride (16B-aligned), rotates banks

// ---------------------------------------------------------------- init
__global__ __launch_bounds__(256) void init_kernel(int* __restrict__ cnt,
                                                   float* __restrict__ sums,
                                                   int* __restrict__ gcnt) {
    int i = blockIdx.x * 256 + threadIdx.x;
    if (i < N_NODES) cnt[i] = 0;
    if (i < NGRAPHS * DIM) sums[i] = 0.f;
    if (i < NGRAPHS) gcnt[i] = 0;
}

// ---------------------------------------------------------------- converts
__global__ __launch_bounds__(256) void cvtX_kernel(const float* __restrict__ X,
                                                   __half* __restrict__ Xh) {
    int i = (blockIdx.x * 256 + threadIdx.x) * 4;
    if (i < N_NODES * DIM) {
        float4 v = *(const float4*)(X + i);
        union { __half2 h2[2]; uint2 u; } pk;
        pk.h2[0] = __floats2half2_rn(v.x, v.y);
        pk.h2[1] = __floats2half2_rn(v.z, v.w);
        *(uint2*)(Xh + i) = pk.u;
    }
}

// WT[(l*3+w)][n][k] = W_w[l][k][n] as fp16 (transposed for B-frag b128 reads)
__global__ __launch_bounds__(256) void cvtW_kernel(const float* __restrict__ Wd,
                                                   const float* __restrict__ Wc,
                                                   const float* __restrict__ Ws,
                                                   __half* __restrict__ WT) {
    int idx = blockIdx.x * 256 + threadIdx.x;
    if (idx < 9 * DIM * DIM) {
        int k  = idx & 127;
        int n  = (idx >> 7) & 127;
        int lw = idx >> 14;          // l*3 + w
        int l  = lw / 3, w = lw - 3 * l;
        const float* W = ((w == 0) ? Wd : (w == 1) ? Wc : Ws)
                         + (size_t)l * DIM * DIM;
        WT[idx] = __float2half(W[k * DIM + n]);
    }
}

// ---------------------------------------------------------------- CSR build
__global__ __launch_bounds__(256) void hist_kernel(const int* __restrict__ dst,
                                                   int* __restrict__ cnt,
                                                   int* __restrict__ rank) {
    int t = blockIdx.x * 256 + threadIdx.x;
    int d[EDGE_BATCH], r[EDGE_BATCH];
#pragma unroll
    for (int i = 0; i < EDGE_BATCH; ++i) d[i] = dst[t + i * EDGE_THREADS];
#pragma unroll
    for (int i = 0; i < EDGE_BATCH; ++i) r[i] = atomicAdd(&cnt[d[i]], 1);
#pragma unroll
    for (int i = 0; i < EDGE_BATCH; ++i) rank[t + i * EDGE_THREADS] = r[i];
}

__global__ __launch_bounds__(256) void scan1_kernel(const int* __restrict__ cnt,
                                                    int* __restrict__ incl,
                                                    int* __restrict__ bsums) {
    __shared__ int sh[256];
    int i = blockIdx.x * 256 + threadIdx.x;
    int v = (i < N_NODES) ? cnt[i] : 0;
    sh[threadIdx.x] = v;
    __syncthreads();
    for (int o = 1; o < 256; o <<= 1) {
        int t = (threadIdx.x >= o) ? sh[threadIdx.x - o] : 0;
        __syncthreads();
        sh[threadIdx.x] += t;
        __syncthreads();
    }
    if (i < N_NODES) incl[i] = sh[threadIdx.x];
    if (threadIdx.x == 255) bsums[blockIdx.x] = sh[255];
}

__global__ __launch_bounds__(256) void scan2_kernel(int* __restrict__ bsums, int nb) {
    __shared__ int sh[256];
    int v = (threadIdx.x < nb) ? bsums[threadIdx.x] : 0;
    sh[threadIdx.x] = v;
    __syncthreads();
    for (int o = 1; o < 256; o <<= 1) {
        int t = (threadIdx.x >= o) ? sh[threadIdx.x - o] : 0;
        __syncthreads();
        sh[threadIdx.x] += t;
        __syncthreads();
    }
    if (threadIdx.x < nb) bsums[threadIdx.x] = sh[threadIdx.x] - v;  // exclusive
}

__global__ __launch_bounds__(256) void scan3_kernel(const int* __restrict__ incl,
                                                    const int* __restrict__ cnt,
                                                    const int* __restrict__ bsums,
                                                    int* __restrict__ row_start) {
    int i = blockIdx.x * 256 + threadIdx.x;
    if (i < N_NODES)
        row_start[i] = incl[i] - cnt[i] + bsums[blockIdx.x];
}

// col packs (type*N + src): direct row index into fp16 Xdc buffer.
__global__ __launch_bounds__(256) void fill_kernel(const int* __restrict__ src,
                                                   const int* __restrict__ dst,
                                                   const int* __restrict__ et,
                                                   const int* __restrict__ rank,
                                                   const int* __restrict__ rowst,
                                                   int* __restrict__ col) {
    int t = blockIdx.x * 256 + threadIdx.x;
    int d[EDGE_BATCH], sv[EDGE_BATCH], rk[EDGE_BATCH], p[EDGE_BATCH];
#pragma unroll
    for (int i = 0; i < EDGE_BATCH; ++i) {
        int e = t + i * EDGE_THREADS;
        d[i]  = dst[e];
        rk[i] = rank[e];
        sv[i] = src[e] + et[e] * N_NODES;
    }
#pragma unroll
    for (int i = 0; i < EDGE_BATCH; ++i) p[i] = rowst[d[i]] + rk[i];
#pragma unroll
    for (int i = 0; i < EDGE_BATCH; ++i) col[p[i]] = sv[i];
}

// ---------------------------------------------------------------- MFMA GEMM
// One weight matrix per blockIdx.y; block = 32 rows x 128 cols, K=128 fully
// resident. Wave computes 32x32 via 4 mfma_f32_16x16x32_f16 accumulators.
// A-frag: A[m=lane&15][k=quad*8+j]; B^T stored [n][k] -> identical indexing;
// C/D: col=lane&15, row=quad*4+reg (m89-verified).
// R6 FIX: staging strides were 16 halves per uint4, but uint4 = 8 halves ->
// half of LDS was uninitialized (absmax inf). Now 16 threads/row x 8 halves.
__global__ __launch_bounds__(256) void gemm3m_kernel(
        const __half* __restrict__ Xh,   // [N][128] fp16
        const __half* __restrict__ WTl,  // [3][128 n][128 k] fp16, this layer
        const float* __restrict__ bd, const float* __restrict__ bc,
        const float* __restrict__ bs,
        __half* __restrict__ Od, __half* __restrict__ Oc,
        __half* __restrict__ Sh) {
    __shared__ _Float16 As[32 * LDK];
    __shared__ _Float16 Bs[128 * LDK];

    const int tid = threadIdx.x;
    const int m0  = blockIdx.x * 32;
    const int w   = blockIdx.y;

    // stage A: 32 rows x 128 halves = 4096 halves; 512 uint4-stores (2/thread)
    {
#pragma unroll
        for (int i = 0; i < 2; ++i) {
            int c    = i * 256 + tid;
            int row  = c >> 4;           // 16 threads per row
            int colh = (c & 15) * 8;     // 8 halves per uint4
            uint4 v  = make_uint4(0u, 0u, 0u, 0u);
            int gr   = m0 + row;
            if (gr < N_NODES) v = *(const uint4*)(Xh + (size_t)gr * DIM + colh);
            *(uint4*)(As + row * LDK + colh) = v;
        }
    }
    // stage B^T: 128 rows x 128 halves = 16384 halves; 2048 uint4 (8/thread)
    {
        const __half* Wt = WTl + (size_t)w * DIM * DIM;
#pragma unroll
        for (int i = 0; i < 8; ++i) {
            int c    = i * 256 + tid;
            int row  = c >> 4;
            int colh = (c & 15) * 8;
            uint4 v = *(const uint4*)(Wt + (size_t)row * DIM + colh);
            *(uint4*)(Bs + row * LDK + colh) = v;
        }
    }
    __syncthreads();

    const int wv = tid >> 6;     // wave id -> cols wv*32..wv*32+31
    const int l  = tid & 63;
    const int lm = l & 15;
    const int q  = l >> 4;

    const float* bias = (w == 0) ? bd : (w == 1) ? bc : bs;
    float b0v = bias[wv * 32 + lm];
    float b1v = bias[wv * 32 + 16 + lm];
    f32x4 acc[2][2];
#pragma unroll
    for (int mt = 0; mt < 2; ++mt) {
        acc[mt][0] = (f32x4){b0v, b0v, b0v, b0v};
        acc[mt][1] = (f32x4){b1v, b1v, b1v, b1v};
    }

#pragma unroll
    for (int ks = 0; ks < 4; ++ks) {
        int coff = ks * 32 + q * 8;
        half8 a0  = *(const half8*)(As + lm * LDK + coff);
        half8 a1  = *(const half8*)(As + (16 + lm) * LDK + coff);
        half8 bb0 = *(const half8*)(Bs + (wv * 32 + lm) * LDK + coff);
        half8 bb1 = *(const half8*)(Bs + (wv * 32 + 16 + lm) * LDK + coff);
        acc[0][0] = __builtin_amdgcn_mfma_f32_16x16x32_f16(a0, bb0, acc[0][0], 0, 0, 0);
        acc[0][1] = __builtin_amdgcn_mfma_f32_16x16x32_f16(a0, bb1, acc[0][1], 0, 0, 0);
        acc[1][0] = __builtin_amdgcn_mfma_f32_16x16x32_f16(a1, bb0, acc[1][0], 0, 0, 0);
        acc[1][1] = __builtin_amdgcn_mfma_f32_16x16x32_f16(a1, bb1, acc[1][1], 0, 0, 0);
    }

    __half* O = (w == 0) ? Od : (w == 1) ? Oc : Sh;
#pragma unroll
    for (int mt = 0; mt < 2; ++mt)
#pragma unroll
        for (int nt = 0; nt < 2; ++nt) {
            int colg = wv * 32 + nt * 16 + lm;
#pragma unroll
            for (int r = 0; r < 4; ++r) {
                int row = m0 + mt * 16 + q * 4 + r;
                if (row < N_NODES)
                    O[(size_t)row * DIM + colg] = __float2half(acc[mt][nt][r]);
            }
        }
}

// ---------------------------------------------------------------- aggregation
// Half-wave (32 lanes) per node, fp16 rows (256 B): uint2 = 4 halves/lane,
// fp32 accumulate, fp16 S self-term, fp16 output X.
__global__ __launch_bounds__(256) void agg_kernel(
        const int* __restrict__ row_start, const int* __restrict__ cnt,
        const int* __restrict__ col,
        const __half* __restrict__ Xdc,
        const __half* __restrict__ Sh, __half* __restrict__ Xout) {
    int wave = (blockIdx.x * 256 + threadIdx.x) >> 6;
    int lane = threadIdx.x & 63;
    int half = lane >> 5;
    int l32  = lane & 31;
    int node = wave * 2 + half;
    if (node >= N_NODES) return;

    int rs  = row_start[node];
    int deg = cnt[node];
    const size_t off = (size_t)l32 * 4;   // in halves

    float4 a[8];
#pragma unroll
    for (int i = 0; i < 8; ++i) a[i] = make_float4(0.f, 0.f, 0.f, 0.f);

    int e = 0;
    for (; e + 8 <= deg; e += 8) {
        int p[8];
#pragma unroll
        for (int i = 0; i < 8; ++i) p[i] = col[rs + e + i];
        union { uint2 u; __half2 h2[2]; } v[8];
#pragma unroll
        for (int i = 0; i < 8; ++i)
            v[i].u = *(const uint2*)(Xdc + (size_t)p[i] * DIM + off);
#pragma unroll
        for (int i = 0; i < 8; ++i) {
            float2 f0 = __half22float2(v[i].h2[0]);
            float2 f1 = __half22float2(v[i].h2[1]);
            a[i].x += f0.x; a[i].y += f0.y;
            a[i].z += f1.x; a[i].w += f1.y;
        }
    }
    for (; e < deg; ++e) {
        int p0 = col[rs + e];
        union { uint2 u; __half2 h2[2]; } v0;
        v0.u = *(const uint2*)(Xdc + (size_t)p0 * DIM + off);
        float2 f0 = __half22float2(v0.h2[0]);
        float2 f1 = __half22float2(v0.h2[1]);
        a[0].x += f0.x; a[0].y += f0.y;
        a[0].z += f1.x; a[0].w += f1.y;
    }

#pragma unroll
    for (int i = 1; i < 8; ++i) {
        a[0].x += a[i].x; a[0].y += a[i].y;
        a[0].z += a[i].z; a[0].w += a[i].w;
    }

    union { uint2 u; __half2 h2[2]; } sv;
    sv.u = *(const uint2*)(Sh + (size_t)node * DIM + off);
    float2 s0 = __half22float2(sv.h2[0]);
    float2 s1 = __half22float2(sv.h2[1]);

    float rx = fmaxf(a[0].x + s0.x, 0.f);
    float ry = fmaxf(a[0].y + s0.y, 0.f);
    float rz = fmaxf(a[0].z + s1.x, 0.f);
    float rw = fmaxf(a[0].w + s1.y, 0.f);

    union { __half2 h2[2]; uint2 u; } pk;
    pk.h2[0] = __floats2half2_rn(rx, ry);
    pk.h2[1] = __floats2half2_rn(rz, rw);
    *(uint2*)(Xout + (size_t)node * DIM + off) = pk.u;
}

// ---------------------------------------------------------------- pooling
__global__ __launch_bounds__(256) void pool_kernel(const __half* __restrict__ X,
                                                   const int* __restrict__ bid,
                                                   float* __restrict__ sums,
                                                   int* __restrict__ gcnt) {
    int tid = threadIdx.x;
    int h   = tid >> 7;
    int d   = tid & 127;
    int n0  = blockIdx.x * 256;
    int end = min(n0 + 256, N_NODES);

    float acc = 0.f;
    int cur = -1, run = 0;
    for (int i = n0 + h; i < end; i += 2) {
        int g = bid[i];
        if (g != cur) {
            if (cur >= 0) {
                atomicAdd(&sums[cur * DIM + d], acc);
                if (d == 0) atomicAdd(&gcnt[cur], run);
            }
            acc = 0.f; run = 0; cur = g;
        }
        acc += __half2float(X[(size_t)i * DIM + d]);
        run++;
    }
    if (cur >= 0) {
        atomicAdd(&sums[cur * DIM + d], acc);
        if (d == 0) atomicAdd(&gcnt[cur], run);
    }
}

__global__ __launch_bounds__(256) void div_kernel(const float* __restrict__ sums,
                                                  const int* __restrict__ gcnt,
                                                  float* __restrict__ out) {
    int i = blockIdx.x * 256 + threadIdx.x;
    if (i < NGRAPHS * DIM) {
        int g = i >> 7;
        out[i] = sums[i] / fmaxf((float)gcnt[g], 1.f);
    }
}

// ---------------------------------------------------------------- launcher
extern "C" void kernel_launch(void* const* d_in, const int* in_sizes, int n_in,
                              void* d_out, int out_size, void* d_ws, size_t ws_size,
                              hipStream_t stream) {
    const float* Xin = (const float*)d_in[0];
    const float* Wd  = (const float*)d_in[1];
    const float* bd  = (const float*)d_in[2];
    const float* Wc  = (const float*)d_in[3];
    const float* bc  = (const float*)d_in[4];
    const float* Ws  = (const float*)d_in[5];
    const float* bs  = (const float*)d_in[6];
    const int* edge_index = (const int*)d_in[7];
    const int* edge_types = (const int*)d_in[8];
    const int* batch_ids  = (const int*)d_in[9];

    const int* src = edge_index;
    const int* dst = edge_index + N_EDGES;

    const size_t NBH = (size_t)N_NODES * DIM * sizeof(__half);  // 12.8 MB
    char* w = (char*)d_ws;
    auto take = [&](size_t bytes) {
        char* p = w;
        w += (bytes + 255) & ~(size_t)255;
        return p;
    };
    __half* X0h  = (__half*)take(NBH);
    __half* Xb0h = (__half*)take(NBH);
    __half* Xb1h = (__half*)take(NBH);
    __half* Xdc  = (__half*)take(2 * NBH);  // rows 0..N = Xd, N..2N = Xc
    __half* Shb  = (__half*)take(NBH);
    __half* WT   = (__half*)take((size_t)9 * DIM * DIM * sizeof(__half));
    int* col     = (int*)take((size_t)N_EDGES * 4);
    int* rank    = (int*)take((size_t)N_EDGES * 4);
    int* cnt     = (int*)take((size_t)N_NODES * 4);
    int* rowst   = (int*)take((size_t)N_NODES * 4);
    int* incl    = (int*)take((size_t)N_NODES * 4);
    int* bsums   = (int*)take(1024);
    float* sums  = (float*)take((size_t)NGRAPHS * DIM * 4);
    int* gcnt    = (int*)take(NGRAPHS * 4);

    const int NBLK_N = (N_NODES + 255) / 256;  // 196

    init_kernel<<<NBLK_N, 256, 0, stream>>>(cnt, sums, gcnt);
    cvtX_kernel<<<(N_NODES * DIM / 4 + 255) / 256, 256, 0, stream>>>(Xin, X0h);
    cvtW_kernel<<<(9 * DIM * DIM + 255) / 256, 256, 0, stream>>>(Wd, Wc, Ws, WT);

    hist_kernel<<<EDGE_BLOCKS, 256, 0, stream>>>(dst, cnt, rank);
    scan1_kernel<<<NBLK_N, 256, 0, stream>>>(cnt, incl, bsums);
    scan2_kernel<<<1, 256, 0, stream>>>(bsums, NBLK_N);
    scan3_kernel<<<NBLK_N, 256, 0, stream>>>(incl, cnt, bsums, rowst);
    fill_kernel<<<EDGE_BLOCKS, 256, 0, stream>>>(src, dst, edge_types, rank,
                                                 rowst, col);

    const int GEMM_MBLK = (N_NODES + 31) / 32;    // 1563
    const int AGG_BLKS  = (N_NODES / 2 + 3) / 4;  // 6250
    const __half* Xcur = X0h;
    __half* bufs[3] = {Xb0h, Xb1h, Xb0h};
    for (int l = 0; l < NLAYERS; ++l) {
        gemm3m_kernel<<<dim3(GEMM_MBLK, 3), 256, 0, stream>>>(
            Xcur, WT + (size_t)l * 3 * DIM * DIM,
            bd + (size_t)l * DIM, bc + (size_t)l * DIM, bs + (size_t)l * DIM,
            Xdc, Xdc + (size_t)N_NODES * DIM, Shb);
        __half* Xnext = bufs[l];
        agg_kernel<<<AGG_BLKS, 256, 0, stream>>>(rowst, cnt, col, Xdc, Shb, Xnext);
        Xcur = Xnext;
    }

    pool_kernel<<<NBLK_N, 256, 0, stream>>>(Xcur, batch_ids, sums, gcnt);
    div_kernel<<<(NGRAPHS * DIM + 255) / 256, 256, 0, stream>>>(sums, gcnt,
                                                                (float*)d_out);
}